// Round 20
// baseline (76.036 us; speedup 1.0000x reference)
//
#include <hip/hip_runtime.h>
#include <hip/hip_bf16.h>
#include <math.h>

#define N_TOK 16384
#define D_DIM 2048
#define E_EXP 64
#define KQ    256               /* K per wave (eighth split) */
#define NCHW  8                 /* K-chunks of 32 per wave */
#define NBLK  256               /* 64-token tiles */

typedef __attribute__((ext_vector_type(8))) short bf16x8;
typedef __attribute__((ext_vector_type(16))) float f32x16;
typedef __attribute__((ext_vector_type(4))) unsigned int u32x4;

// pack two masked fp32 bit-patterns' high halves into one u32 of 2 bf16
#define PACK2(HI, LO) __builtin_amdgcn_perm((HI), (LO), 0x07060302u)

typedef union { unsigned u[4]; bf16x8 v; } b8u;

// ---------------------------------------------------------------------------
// pack_w: W fp32 [64][2048] -> exact 3-limb bf16 split, frag-ordered for
// 32x32x16 B-frags: ushort off = c*6144 + ks*3072 + tau*1024 + kgrp*512 + e*8.
// Split is EXACT; only ml/lm/ll cross terms dropped. Verified R10-R19.
// Block 0 zero-inits the f64/u32 accumulators AND the done-counter
// (stream order guarantees completion before fused_router launches).
// ---------------------------------------------------------------------------
__global__ void pack_w(const float* __restrict__ W,
                       unsigned short* __restrict__ Wp,
                       double* __restrict__ p_sum_d,
                       double* __restrict__ lsesq_d,
                       unsigned* __restrict__ freq,
                       unsigned* __restrict__ done_ctr) {
  if (blockIdx.x == 0 && threadIdx.x < 64) {
    p_sum_d[threadIdx.x] = 0.0;
    freq[threadIdx.x] = 0u;
    if (threadIdx.x == 0) { lsesq_d[0] = 0.0; done_ctr[0] = 0u; }
  }
  const int T = blockIdx.x * 256 + threadIdx.x;   // 16384 = 64c * 4j * 64e
  const int e = T & 63, j = (T >> 6) & 3, c = T >> 8;
  const float* src = W + (size_t)e * D_DIM + c * 32 + j * 8;
  float4 v0 = *(const float4*)src;
  float4 v1 = *(const float4*)(src + 4);
  float vv[8] = {v0.x, v0.y, v0.z, v0.w, v1.x, v1.y, v1.z, v1.w};
  unsigned hu[8], mu[8], lu[8];
#pragma unroll
  for (int q = 0; q < 8; ++q) {
    unsigned u = __float_as_uint(vv[q]);
    unsigned a = u & 0xffff0000u;
    float r = vv[q] - __uint_as_float(a);
    unsigned b = __float_as_uint(r) & 0xffff0000u;
    float r2 = r - __uint_as_float(b);
    unsigned d = __float_as_uint(r2) & 0xffff0000u;
    hu[q] = a; mu[q] = b; lu[q] = d;
  }
  u32x4 ph, pm, pl;
#pragma unroll
  for (int q = 0; q < 4; ++q) {     // ascending k pairs: lo k in low 16
    ph[q] = PACK2(hu[2 * q + 1], hu[2 * q]);
    pm[q] = PACK2(mu[2 * q + 1], mu[2 * q]);
    pl[q] = PACK2(lu[2 * q + 1], lu[2 * q]);
  }
  const size_t base = (size_t)c * 6144 + (j >> 1) * 3072 + (j & 1) * 512 + e * 8;
  *(u32x4*)(Wp + base)        = ph;   // tau 0
  *(u32x4*)(Wp + base + 1024) = pm;   // tau 1
  *(u32x4*)(Wp + base + 2048) = pl;   // tau 2
}

// ---------------------------------------------------------------------------
// Fused GEMM + gating + inline finalize. Main loop = R11/R16 VERBATIM
// (measured best 51.1us; 8 structural variants R12-R15/R17-R19 all
// regressed or were neutral -- it is a local optimum vs this compiler).
// R20 delta: the finalize kernel is folded into the LAST block to finish
// (done-counter + threadfence; accumulators re-read with AGENT-scoped
// atomic loads since per-XCD L2 is not coherent for memory-side atomics).
// grid = 256 blocks x 512 thr (8 waves = K-eighths); 64tok x 64exp block.
// ---------------------------------------------------------------------------
struct XS { float4 a0, a1, b0, b1, c0, c1, d0, d1; };

__global__ __launch_bounds__(512)
void fused_router(const float* __restrict__ x,
                  const unsigned short* __restrict__ Wp,
                  float* __restrict__ out,
                  double* __restrict__ p_sum_d,
                  double* __restrict__ lsesq_d,
                  unsigned* __restrict__ freq,
                  unsigned* __restrict__ done_ctr,
                  float* __restrict__ out_loss) {
  __shared__ float s_c[2][64][66];                 // 33.8 KB, staged combine
  __shared__ float s_m[64], s_inv[64];
  __shared__ unsigned hist[64];
  __shared__ int s_last;
  const int tid  = threadIdx.x;
  const int lane = tid & 63;
  const int kq   = tid >> 6;      // wave = K-eighth
  const int T0   = blockIdx.x * 64;
  if (tid < 64) hist[tid] = 0u;

  const int r  = lane & 31;       // token row within 32-tile / expert col
  const int kg = lane >> 5;       // k-group (0/1) within K=16 step
  const float* xg0 = x + (size_t)(T0 + r) * D_DIM + kq * KQ + kg * 8;
  const float* xg1 = xg0 + (size_t)32 * D_DIM;
  const unsigned short* bp =
      Wp + (size_t)(kq * NCHW) * 6144 + kg * 512 + r * 8;

  f32x16 acc00 = (f32x16)0.f, acc01 = (f32x16)0.f;   // rows 0-31 x e-halves
  f32x16 acc10 = (f32x16)0.f, acc11 = (f32x16)0.f;   // rows 32-63

#define CVT8(V0, V1, OH, OM, OL)                                            \
  do {                                                                      \
    float vv[8] = {(V0).x, (V0).y, (V0).z, (V0).w,                          \
                   (V1).x, (V1).y, (V1).z, (V1).w};                         \
    unsigned hu[8], mu[8], lu[8];                                           \
    _Pragma("unroll") for (int q = 0; q < 8; ++q) {                         \
      unsigned u = __float_as_uint(vv[q]);                                  \
      unsigned a = u & 0xffff0000u;                                         \
      float rr = vv[q] - __uint_as_float(a);                                \
      unsigned b = __float_as_uint(rr) & 0xffff0000u;                       \
      float r2 = rr - __uint_as_float(b);                                   \
      unsigned d = __float_as_uint(r2) & 0xffff0000u;                       \
      hu[q] = a; mu[q] = b; lu[q] = d;                                      \
    }                                                                       \
    b8u th, tm, tl;                                                         \
    _Pragma("unroll") for (int q = 0; q < 4; ++q) {                         \
      th.u[q] = PACK2(hu[2 * q + 1], hu[2 * q]);                            \
      tm.u[q] = PACK2(mu[2 * q + 1], mu[2 * q]);                            \
      tl.u[q] = PACK2(lu[2 * q + 1], lu[2 * q]);                            \
    }                                                                       \
    OH = th.v; OM = tm.v; OL = tl.v;                                        \
  } while (0)

#define MM6(AH, AM, AL, BH, BM, BL, ACC)                                      \
    ACC = __builtin_amdgcn_mfma_f32_32x32x16_bf16(AH, BH, ACC, 0, 0, 0);      \
    ACC = __builtin_amdgcn_mfma_f32_32x32x16_bf16(AH, BM, ACC, 0, 0, 0);      \
    ACC = __builtin_amdgcn_mfma_f32_32x32x16_bf16(AM, BH, ACC, 0, 0, 0);      \
    ACC = __builtin_amdgcn_mfma_f32_32x32x16_bf16(AH, BL, ACC, 0, 0, 0);      \
    ACC = __builtin_amdgcn_mfma_f32_32x32x16_bf16(AM, BM, ACC, 0, 0, 0);      \
    ACC = __builtin_amdgcn_mfma_f32_32x32x16_bf16(AL, BH, ACC, 0, 0, 0)

#define LOADX(S, C)                                                         \
  do {                                                                      \
    const float* p0_ = xg0 + (C) * 32;                                      \
    const float* p1_ = xg1 + (C) * 32;                                      \
    S.a0 = *(const float4*)(p0_);      S.a1 = *(const float4*)(p0_ + 4);    \
    S.b0 = *(const float4*)(p0_ + 16); S.b1 = *(const float4*)(p0_ + 20);   \
    S.c0 = *(const float4*)(p1_);      S.c1 = *(const float4*)(p1_ + 4);    \
    S.d0 = *(const float4*)(p1_ + 16); S.d1 = *(const float4*)(p1_ + 20);   \
  } while (0)

#define BODY(C, XU, XN, DOPRE)                                              \
  {                                                                         \
    const unsigned short* bc = bp + (size_t)(C) * 6144;                     \
    bf16x8 B00h = *(const bf16x8*)(bc);                                     \
    bf16x8 B00m = *(const bf16x8*)(bc + 1024);                              \
    bf16x8 B00l = *(const bf16x8*)(bc + 2048);                              \
    bf16x8 B01h = *(const bf16x8*)(bc + 256);                               \
    bf16x8 B01m = *(const bf16x8*)(bc + 256 + 1024);                        \
    bf16x8 B01l = *(const bf16x8*)(bc + 256 + 2048);                        \
    bf16x8 B10h = *(const bf16x8*)(bc + 3072);                              \
    bf16x8 B10m = *(const bf16x8*)(bc + 3072 + 1024);                       \
    bf16x8 B10l = *(const bf16x8*)(bc + 3072 + 2048);                       \
    bf16x8 B11h = *(const bf16x8*)(bc + 3072 + 256);                        \
    bf16x8 B11m = *(const bf16x8*)(bc + 3072 + 256 + 1024);                 \
    bf16x8 B11l = *(const bf16x8*)(bc + 3072 + 256 + 2048);                 \
    if (DOPRE) LOADX(XN, (C) + 1);  /* T14: issue-early, use next iter */   \
    {                                                                       \
      bf16x8 A0h, A0m, A0l, A1h, A1m, A1l;                                  \
      CVT8(XU.a0, XU.a1, A0h, A0m, A0l);   /* rows 0-31, kstep 0 */         \
      CVT8(XU.b0, XU.b1, A1h, A1m, A1l);   /* rows 0-31, kstep 1 */         \
      MM6(A0h, A0m, A0l, B00h, B00m, B00l, acc00);                          \
      MM6(A0h, A0m, A0l, B01h, B01m, B01l, acc01);                          \
      MM6(A1h, A1m, A1l, B10h, B10m, B10l, acc00);                          \
      MM6(A1h, A1m, A1l, B11h, B11m, B11l, acc01);                          \
    }                                                                       \
    {                                                                       \
      bf16x8 A0h, A0m, A0l, A1h, A1m, A1l;                                  \
      CVT8(XU.c0, XU.c1, A0h, A0m, A0l);   /* rows 32-63, kstep 0 */        \
      CVT8(XU.d0, XU.d1, A1h, A1m, A1l);   /* rows 32-63, kstep 1 */        \
      MM6(A0h, A0m, A0l, B00h, B00m, B00l, acc10);                          \
      MM6(A0h, A0m, A0l, B01h, B01m, B01l, acc11);                          \
      MM6(A1h, A1m, A1l, B10h, B10m, B10l, acc10);                          \
      MM6(A1h, A1m, A1l, B11h, B11m, B11l, acc11);                          \
    }                                                                       \
  }

  XS xA, xB;
  LOADX(xA, 0);
#pragma unroll
  for (int cc = 0; cc < NCHW; cc += 2) {
    BODY(cc, xA, xB, (cc + 1) < NCHW);
    BODY(cc + 1, xB, xA, (cc + 2) < NCHW);
  }
#undef BODY
#undef LOADX
#undef MM6
#undef CVT8

  // ---- staged 2-slot combine of 8 K-partials ----
  // C/D row-in-tile = (reg&3) + 8*(reg>>2) + 4*kg  [m74/m101-verified]
  const int slot = kq & 1;
#define SCAT(OP)                                                            \
  _Pragma("unroll") for (int reg = 0; reg < 16; ++reg) {                    \
    const int tl_ = (reg & 3) + 8 * (reg >> 2) + 4 * kg;                    \
    s_c[slot][tl_][r]           OP acc00[reg];                              \
    s_c[slot][tl_][32 + r]      OP acc01[reg];                              \
    s_c[slot][32 + tl_][r]      OP acc10[reg];                              \
    s_c[slot][32 + tl_][32 + r] OP acc11[reg];                              \
  }
  if (kq < 2) SCAT(=);
  __syncthreads();
  if (kq == 2 || kq == 3) SCAT(+=);
  __syncthreads();
  if (kq == 4 || kq == 5) SCAT(+=);
  __syncthreads();
  if (kq == 6 || kq == 7) SCAT(+=);
  __syncthreads();
#undef SCAT
  {   // fold slot1 into slot0: all 512 threads
    const int t = tid >> 3, e0 = (tid & 7) * 8;
#pragma unroll
    for (int q = 0; q < 8; ++q)
      s_c[0][t][e0 + q] += s_c[1][t][e0 + q];
  }
  __syncthreads();

  // ---- per-token: softmax stats, top-2, gates (R9-R19-proven) ----
  if (tid < 64) {
    const int t = tid;
    float m = -3.402823466e38f;
#pragma unroll
    for (int e = 0; e < 64; ++e) m = fmaxf(m, s_c[0][t][e]);
    float sum = 0.f;
#pragma unroll
    for (int e = 0; e < 64; ++e) sum += __expf(s_c[0][t][e] - m);
    const float lse = m + __logf(sum);
    const float inv = 1.0f / sum;
    s_m[t] = m;
    s_inv[t] = inv;

    float v0 = s_c[0][t][0], v1 = -3.402823466e38f;
    int i0 = 0, i1 = 0;
#pragma unroll
    for (int e = 1; e < 64; ++e) {   // strict > keeps lowest idx (lax.top_k)
      float le = s_c[0][t][e];
      bool g0 = le > v0;
      bool g1 = le > v1;
      float nv1 = g0 ? v0 : (g1 ? le : v1);
      int   ni1 = g0 ? i0 : (g1 ? e  : i1);
      v0 = g0 ? le : v0;
      i0 = g0 ? e  : i0;
      v1 = nv1; i1 = ni1;
    }
    float dd = __expf(v1 - v0);
    float g0 = 1.0f / (1.0f + dd);
    float g1 = dd * g0;

    const int tg = T0 + t;
    out[tg * 2 + 0] = (float)i0;
    out[tg * 2 + 1] = (float)i1;
    out[2 * N_TOK + tg * 2 + 0] = g0;
    out[2 * N_TOK + tg * 2 + 1] = g1;

    atomicAdd(&hist[i0], 1u);
    atomicAdd(&hist[i1], 1u);

    float z = lse * lse;
    z += __shfl_xor(z, 32, 64);
    z += __shfl_xor(z, 16, 64);
    z += __shfl_xor(z, 8, 64);
    z += __shfl_xor(z, 4, 64);
    z += __shfl_xor(z, 2, 64);
    z += __shfl_xor(z, 1, 64);
    if (tid == 0) atomicAdd(lsesq_d, (double)z);
  }
  __syncthreads();

  // ---- per-expert prob column sums (wave 1): f64 atomic, 64 disjoint ----
  if (tid >= 64 && tid < 128) {
    const int e = tid - 64;
    float cs2 = 0.f;
#pragma unroll 8
    for (int t = 0; t < 64; ++t)
      cs2 += __expf(s_c[0][t][e] - s_m[t]) * s_inv[t];
    atomicAdd(&p_sum_d[e], (double)cs2);
  }
  if (tid < 64 && hist[tid]) atomicAdd(&freq[tid], hist[tid]);

  // ---- inline finalize: last block to arrive computes the loss ----
  __threadfence();              // make this block's atomics globally visible
  __syncthreads();              // all waves' atomics issued before counting
  if (tid == 0) {
    unsigned prev = atomicAdd(done_ctr, 1u);
    s_last = (prev == NBLK - 1);
  }
  __syncthreads();
  if (s_last && tid < 64) {
    __threadfence();            // acquire: see all other blocks' atomics
    double p = __hip_atomic_load(&p_sum_d[tid], __ATOMIC_RELAXED,
                                 __HIP_MEMORY_SCOPE_AGENT);
    double f = (double)__hip_atomic_load(&freq[tid], __ATOMIC_RELAXED,
                                         __HIP_MEMORY_SCOPE_AGENT);
    double pa = fabs(p);
    double fa = fabs(f);
#pragma unroll
    for (int off = 32; off >= 1; off >>= 1) {
      pa += __shfl_xor(pa, off, 64);
      fa += __shfl_xor(fa, off, 64);
    }
    pa = pa > 1e-12 ? pa : 1e-12;
    fa = fa > 1e-12 ? fa : 1e-12;

    double s = (p / pa) * (f / fa);
#pragma unroll
    for (int off = 32; off >= 1; off >>= 1) s += __shfl_xor(s, off, 64);

    if (tid == 0) {
      double zt = __hip_atomic_load(lsesq_d, __ATOMIC_RELAXED,
                                    __HIP_MEMORY_SCOPE_AGENT);
      double switchloss = 64.0 * s;
      double z_loss = zt / (double)N_TOK;
      out_loss[0] = (float)(switchloss + 0.1 * z_loss);
    }
  }
}

extern "C" void kernel_launch(void* const* d_in, const int* in_sizes, int n_in,
                              void* d_out, int out_size, void* d_ws, size_t ws_size,
                              hipStream_t stream) {
  const float* x = (const float*)d_in[0];
  const float* W = (const float*)d_in[1];
  float* out = (float*)d_out;

  double* p_sum_d = (double*)d_ws;                       // 512 B
  double* lsesq_d = p_sum_d + 64;                        // 8 B
  unsigned* freq  = (unsigned*)(lsesq_d + 1);            // 256 B
  unsigned* done_ctr = freq + 64;                        // 4 B
  size_t woff = (64 * 8 + 8 + 64 * 4 + 4 + 255) & ~(size_t)255;
  unsigned short* Wp = (unsigned short*)((char*)d_ws + woff);  // 768 KB

  pack_w<<<64, 256, 0, stream>>>(W, Wp, p_sum_d, lsesq_d, freq, done_ctr);
  fused_router<<<NBLK, 512, 0, stream>>>(x, Wp, out, p_sum_d, lsesq_d, freq,
                                         done_ctr, out + 4 * N_TOK);
}

// Round 21
// 50.868 us; speedup vs baseline: 1.4948x; 1.4948x over previous
//
#include <hip/hip_runtime.h>
#include <hip/hip_bf16.h>
#include <math.h>

#define N_TOK 16384
#define D_DIM 2048
#define E_EXP 64
#define KQ    256               /* K per wave (eighth split) */
#define NCHW  8                 /* K-chunks of 32 per wave */
#define NBLK  256               /* 64-token tiles */

typedef __attribute__((ext_vector_type(8))) short bf16x8;
typedef __attribute__((ext_vector_type(16))) float f32x16;
typedef __attribute__((ext_vector_type(4))) unsigned int u32x4;

// pack two masked fp32 bit-patterns' high halves into one u32 of 2 bf16
#define PACK2(HI, LO) __builtin_amdgcn_perm((HI), (LO), 0x07060302u)

typedef union { unsigned u[4]; bf16x8 v; } b8u;

// ---------------------------------------------------------------------------
// pack_w: W fp32 [64][2048] -> exact 3-limb bf16 split, frag-ordered for
// 32x32x16 B-frags: ushort off = c*6144 + ks*3072 + tau*1024 + kgrp*512 + e*8.
// Split is EXACT; only ml/lm/ll cross terms dropped. Verified R10-R20.
// Block 0 zero-inits the f64/u32 accumulators (stream order guarantees
// completion before fused_router launches).
// ---------------------------------------------------------------------------
__global__ void pack_w(const float* __restrict__ W,
                       unsigned short* __restrict__ Wp,
                       double* __restrict__ p_sum_d,
                       double* __restrict__ lsesq_d,
                       unsigned* __restrict__ freq) {
  if (blockIdx.x == 0 && threadIdx.x < 64) {
    p_sum_d[threadIdx.x] = 0.0;
    freq[threadIdx.x] = 0u;
    if (threadIdx.x == 0) lsesq_d[0] = 0.0;
  }
  const int T = blockIdx.x * 256 + threadIdx.x;   // 16384 = 64c * 4j * 64e
  const int e = T & 63, j = (T >> 6) & 3, c = T >> 8;
  const float* src = W + (size_t)e * D_DIM + c * 32 + j * 8;
  float4 v0 = *(const float4*)src;
  float4 v1 = *(const float4*)(src + 4);
  float vv[8] = {v0.x, v0.y, v0.z, v0.w, v1.x, v1.y, v1.z, v1.w};
  unsigned hu[8], mu[8], lu[8];
#pragma unroll
  for (int q = 0; q < 8; ++q) {
    unsigned u = __float_as_uint(vv[q]);
    unsigned a = u & 0xffff0000u;
    float r = vv[q] - __uint_as_float(a);
    unsigned b = __float_as_uint(r) & 0xffff0000u;
    float r2 = r - __uint_as_float(b);
    unsigned d = __float_as_uint(r2) & 0xffff0000u;
    hu[q] = a; mu[q] = b; lu[q] = d;
  }
  u32x4 ph, pm, pl;
#pragma unroll
  for (int q = 0; q < 4; ++q) {     // ascending k pairs: lo k in low 16
    ph[q] = PACK2(hu[2 * q + 1], hu[2 * q]);
    pm[q] = PACK2(mu[2 * q + 1], mu[2 * q]);
    pl[q] = PACK2(lu[2 * q + 1], lu[2 * q]);
  }
  const size_t base = (size_t)c * 6144 + (j >> 1) * 3072 + (j & 1) * 512 + e * 8;
  *(u32x4*)(Wp + base)        = ph;   // tau 0
  *(u32x4*)(Wp + base + 1024) = pm;   // tau 1
  *(u32x4*)(Wp + base + 2048) = pl;   // tau 2
}

// ---------------------------------------------------------------------------
// Fused GEMM + gating -- R16 VERBATIM (measured best, 51.1us). Main loop =
// R11 structure: no LDS/barriers in main loop; lane gathers A rows
// (row=lane&31, kgroup=lane>>5; k-permutation cancels between A and B),
// limb-splits in regs, mfma_f32_32x32x16_bf16; B streams from L2-resident
// packed Wp; 2-state chunk-32 x prefetch. Epilogue: staged SCAT combine,
// in-block top2/gates, f64 global atomics for p_sum/lse^2 (64 disjoint
// addrs). NOTE (R20 lesson): do NOT graft extra code paths onto this
// kernel -- the inline-finalize variant flipped regalloc to 84 VGPR and
// cost +25us. The separate 1-wave finalize dispatch is the cheap option.
// grid = 256 blocks x 512 thr (8 waves = K-eighths); 64tok x 64exp block.
// ---------------------------------------------------------------------------
struct XS { float4 a0, a1, b0, b1, c0, c1, d0, d1; };

__global__ __launch_bounds__(512)
void fused_router(const float* __restrict__ x,
                  const unsigned short* __restrict__ Wp,
                  float* __restrict__ out,
                  double* __restrict__ p_sum_d,
                  double* __restrict__ lsesq_d,
                  unsigned* __restrict__ freq) {
  __shared__ float s_c[2][64][66];                 // 33.8 KB, staged combine
  __shared__ float s_m[64], s_inv[64];
  __shared__ unsigned hist[64];
  const int tid  = threadIdx.x;
  const int lane = tid & 63;
  const int kq   = tid >> 6;      // wave = K-eighth
  const int T0   = blockIdx.x * 64;
  if (tid < 64) hist[tid] = 0u;

  const int r  = lane & 31;       // token row within 32-tile / expert col
  const int kg = lane >> 5;       // k-group (0/1) within K=16 step
  const float* xg0 = x + (size_t)(T0 + r) * D_DIM + kq * KQ + kg * 8;
  const float* xg1 = xg0 + (size_t)32 * D_DIM;
  const unsigned short* bp =
      Wp + (size_t)(kq * NCHW) * 6144 + kg * 512 + r * 8;

  f32x16 acc00 = (f32x16)0.f, acc01 = (f32x16)0.f;   // rows 0-31 x e-halves
  f32x16 acc10 = (f32x16)0.f, acc11 = (f32x16)0.f;   // rows 32-63

#define CVT8(V0, V1, OH, OM, OL)                                            \
  do {                                                                      \
    float vv[8] = {(V0).x, (V0).y, (V0).z, (V0).w,                          \
                   (V1).x, (V1).y, (V1).z, (V1).w};                         \
    unsigned hu[8], mu[8], lu[8];                                           \
    _Pragma("unroll") for (int q = 0; q < 8; ++q) {                         \
      unsigned u = __float_as_uint(vv[q]);                                  \
      unsigned a = u & 0xffff0000u;                                         \
      float rr = vv[q] - __uint_as_float(a);                                \
      unsigned b = __float_as_uint(rr) & 0xffff0000u;                       \
      float r2 = rr - __uint_as_float(b);                                   \
      unsigned d = __float_as_uint(r2) & 0xffff0000u;                       \
      hu[q] = a; mu[q] = b; lu[q] = d;                                      \
    }                                                                       \
    b8u th, tm, tl;                                                         \
    _Pragma("unroll") for (int q = 0; q < 4; ++q) {                         \
      th.u[q] = PACK2(hu[2 * q + 1], hu[2 * q]);                            \
      tm.u[q] = PACK2(mu[2 * q + 1], mu[2 * q]);                            \
      tl.u[q] = PACK2(lu[2 * q + 1], lu[2 * q]);                            \
    }                                                                       \
    OH = th.v; OM = tm.v; OL = tl.v;                                        \
  } while (0)

#define MM6(AH, AM, AL, BH, BM, BL, ACC)                                      \
    ACC = __builtin_amdgcn_mfma_f32_32x32x16_bf16(AH, BH, ACC, 0, 0, 0);      \
    ACC = __builtin_amdgcn_mfma_f32_32x32x16_bf16(AH, BM, ACC, 0, 0, 0);      \
    ACC = __builtin_amdgcn_mfma_f32_32x32x16_bf16(AM, BH, ACC, 0, 0, 0);      \
    ACC = __builtin_amdgcn_mfma_f32_32x32x16_bf16(AH, BL, ACC, 0, 0, 0);      \
    ACC = __builtin_amdgcn_mfma_f32_32x32x16_bf16(AM, BM, ACC, 0, 0, 0);      \
    ACC = __builtin_amdgcn_mfma_f32_32x32x16_bf16(AL, BH, ACC, 0, 0, 0)

#define LOADX(S, C)                                                         \
  do {                                                                      \
    const float* p0_ = xg0 + (C) * 32;                                      \
    const float* p1_ = xg1 + (C) * 32;                                      \
    S.a0 = *(const float4*)(p0_);      S.a1 = *(const float4*)(p0_ + 4);    \
    S.b0 = *(const float4*)(p0_ + 16); S.b1 = *(const float4*)(p0_ + 20);   \
    S.c0 = *(const float4*)(p1_);      S.c1 = *(const float4*)(p1_ + 4);    \
    S.d0 = *(const float4*)(p1_ + 16); S.d1 = *(const float4*)(p1_ + 20);   \
  } while (0)

#define BODY(C, XU, XN, DOPRE)                                              \
  {                                                                         \
    const unsigned short* bc = bp + (size_t)(C) * 6144;                     \
    bf16x8 B00h = *(const bf16x8*)(bc);                                     \
    bf16x8 B00m = *(const bf16x8*)(bc + 1024);                              \
    bf16x8 B00l = *(const bf16x8*)(bc + 2048);                              \
    bf16x8 B01h = *(const bf16x8*)(bc + 256);                               \
    bf16x8 B01m = *(const bf16x8*)(bc + 256 + 1024);                        \
    bf16x8 B01l = *(const bf16x8*)(bc + 256 + 2048);                        \
    bf16x8 B10h = *(const bf16x8*)(bc + 3072);                              \
    bf16x8 B10m = *(const bf16x8*)(bc + 3072 + 1024);                       \
    bf16x8 B10l = *(const bf16x8*)(bc + 3072 + 2048);                       \
    bf16x8 B11h = *(const bf16x8*)(bc + 3072 + 256);                        \
    bf16x8 B11m = *(const bf16x8*)(bc + 3072 + 256 + 1024);                 \
    bf16x8 B11l = *(const bf16x8*)(bc + 3072 + 256 + 2048);                 \
    if (DOPRE) LOADX(XN, (C) + 1);  /* T14: issue-early, use next iter */   \
    {                                                                       \
      bf16x8 A0h, A0m, A0l, A1h, A1m, A1l;                                  \
      CVT8(XU.a0, XU.a1, A0h, A0m, A0l);   /* rows 0-31, kstep 0 */         \
      CVT8(XU.b0, XU.b1, A1h, A1m, A1l);   /* rows 0-31, kstep 1 */         \
      MM6(A0h, A0m, A0l, B00h, B00m, B00l, acc00);                          \
      MM6(A0h, A0m, A0l, B01h, B01m, B01l, acc01);                          \
      MM6(A1h, A1m, A1l, B10h, B10m, B10l, acc00);                          \
      MM6(A1h, A1m, A1l, B11h, B11m, B11l, acc01);                          \
    }                                                                       \
    {                                                                       \
      bf16x8 A0h, A0m, A0l, A1h, A1m, A1l;                                  \
      CVT8(XU.c0, XU.c1, A0h, A0m, A0l);   /* rows 32-63, kstep 0 */        \
      CVT8(XU.d0, XU.d1, A1h, A1m, A1l);   /* rows 32-63, kstep 1 */        \
      MM6(A0h, A0m, A0l, B00h, B00m, B00l, acc10);                          \
      MM6(A0h, A0m, A0l, B01h, B01m, B01l, acc11);                          \
      MM6(A1h, A1m, A1l, B10h, B10m, B10l, acc10);                          \
      MM6(A1h, A1m, A1l, B11h, B11m, B11l, acc11);                          \
    }                                                                       \
  }

  XS xA, xB;
  LOADX(xA, 0);
#pragma unroll
  for (int cc = 0; cc < NCHW; cc += 2) {
    BODY(cc, xA, xB, (cc + 1) < NCHW);
    BODY(cc + 1, xB, xA, (cc + 2) < NCHW);
  }
#undef BODY
#undef LOADX
#undef MM6
#undef CVT8

  // ---- staged 2-slot combine of 8 K-partials ----
  // C/D row-in-tile = (reg&3) + 8*(reg>>2) + 4*kg  [m74/m101-verified]
  const int slot = kq & 1;
#define SCAT(OP)                                                            \
  _Pragma("unroll") for (int reg = 0; reg < 16; ++reg) {                    \
    const int tl_ = (reg & 3) + 8 * (reg >> 2) + 4 * kg;                    \
    s_c[slot][tl_][r]           OP acc00[reg];                              \
    s_c[slot][tl_][32 + r]      OP acc01[reg];                              \
    s_c[slot][32 + tl_][r]      OP acc10[reg];                              \
    s_c[slot][32 + tl_][32 + r] OP acc11[reg];                              \
  }
  if (kq < 2) SCAT(=);
  __syncthreads();
  if (kq == 2 || kq == 3) SCAT(+=);
  __syncthreads();
  if (kq == 4 || kq == 5) SCAT(+=);
  __syncthreads();
  if (kq == 6 || kq == 7) SCAT(+=);
  __syncthreads();
#undef SCAT
  {   // fold slot1 into slot0: all 512 threads
    const int t = tid >> 3, e0 = (tid & 7) * 8;
#pragma unroll
    for (int q = 0; q < 8; ++q)
      s_c[0][t][e0 + q] += s_c[1][t][e0 + q];
  }
  __syncthreads();

  // ---- per-token: softmax stats, top-2, gates (R9-R20-proven) ----
  if (tid < 64) {
    const int t = tid;
    float m = -3.402823466e38f;
#pragma unroll
    for (int e = 0; e < 64; ++e) m = fmaxf(m, s_c[0][t][e]);
    float sum = 0.f;
#pragma unroll
    for (int e = 0; e < 64; ++e) sum += __expf(s_c[0][t][e] - m);
    const float lse = m + __logf(sum);
    const float inv = 1.0f / sum;
    s_m[t] = m;
    s_inv[t] = inv;

    float v0 = s_c[0][t][0], v1 = -3.402823466e38f;
    int i0 = 0, i1 = 0;
#pragma unroll
    for (int e = 1; e < 64; ++e) {   // strict > keeps lowest idx (lax.top_k)
      float le = s_c[0][t][e];
      bool g0 = le > v0;
      bool g1 = le > v1;
      float nv1 = g0 ? v0 : (g1 ? le : v1);
      int   ni1 = g0 ? i0 : (g1 ? e  : i1);
      v0 = g0 ? le : v0;
      i0 = g0 ? e  : i0;
      v1 = nv1; i1 = ni1;
    }
    float dd = __expf(v1 - v0);
    float g0 = 1.0f / (1.0f + dd);
    float g1 = dd * g0;

    const int tg = T0 + t;
    out[tg * 2 + 0] = (float)i0;
    out[tg * 2 + 1] = (float)i1;
    out[2 * N_TOK + tg * 2 + 0] = g0;
    out[2 * N_TOK + tg * 2 + 1] = g1;

    atomicAdd(&hist[i0], 1u);
    atomicAdd(&hist[i1], 1u);

    float z = lse * lse;
    z += __shfl_xor(z, 32, 64);
    z += __shfl_xor(z, 16, 64);
    z += __shfl_xor(z, 8, 64);
    z += __shfl_xor(z, 4, 64);
    z += __shfl_xor(z, 2, 64);
    z += __shfl_xor(z, 1, 64);
    if (tid == 0) atomicAdd(lsesq_d, (double)z);
  }
  __syncthreads();

  // ---- per-expert prob column sums (wave 1): f64 atomic, 64 disjoint ----
  if (tid >= 64 && tid < 128) {
    const int e = tid - 64;
    float cs2 = 0.f;
#pragma unroll 8
    for (int t = 0; t < 64; ++t)
      cs2 += __expf(s_c[0][t][e] - s_m[t]) * s_inv[t];
    atomicAdd(&p_sum_d[e], (double)cs2);
  }
  if (tid < 64 && hist[tid]) atomicAdd(&freq[tid], hist[tid]);
}

// ---------------------------------------------------------------------------
// Finalize: loop-free single wave. switchloss + 0.1 * z_loss.
// ---------------------------------------------------------------------------
__global__ void finalize(const double* __restrict__ p_sum_d,
                         const double* __restrict__ lsesq_d,
                         const unsigned* __restrict__ freq,
                         float* __restrict__ out_loss) {
  const int lane = threadIdx.x;
  double p = p_sum_d[lane];
  double f = (double)freq[lane];

  double pa = fabs(p);
  double fa = fabs(f);
#pragma unroll
  for (int off = 32; off >= 1; off >>= 1) {
    pa += __shfl_xor(pa, off, 64);
    fa += __shfl_xor(fa, off, 64);
  }
  pa = pa > 1e-12 ? pa : 1e-12;
  fa = fa > 1e-12 ? fa : 1e-12;

  double s = (p / pa) * (f / fa);
#pragma unroll
  for (int off = 32; off >= 1; off >>= 1) s += __shfl_xor(s, off, 64);

  if (lane == 0) {
    double switchloss = 64.0 * s;
    double z_loss = lsesq_d[0] / (double)N_TOK;
    out_loss[0] = (float)(switchloss + 0.1 * z_loss);
  }
}

extern "C" void kernel_launch(void* const* d_in, const int* in_sizes, int n_in,
                              void* d_out, int out_size, void* d_ws, size_t ws_size,
                              hipStream_t stream) {
  const float* x = (const float*)d_in[0];
  const float* W = (const float*)d_in[1];
  float* out = (float*)d_out;

  double* p_sum_d = (double*)d_ws;                       // 512 B
  double* lsesq_d = p_sum_d + 64;                        // 8 B
  unsigned* freq  = (unsigned*)(lsesq_d + 1);            // 256 B
  size_t woff = (64 * 8 + 8 + 64 * 4 + 255) & ~(size_t)255;
  unsigned short* Wp = (unsigned short*)((char*)d_ws + woff);  // 768 KB

  pack_w<<<64, 256, 0, stream>>>(W, Wp, p_sum_d, lsesq_d, freq);
  fused_router<<<NBLK, 512, 0, stream>>>(x, Wp, out, p_sum_d, lsesq_d, freq);
  finalize<<<1, 64, 0, stream>>>(p_sum_d, lsesq_d, freq, out + 4 * N_TOK);
}